// Round 1
// baseline (704.084 us; speedup 1.0000x reference)
//
#include <hip/hip_runtime.h>
#include <hip/hip_bf16.h>

// SageNet: 4-layer GraphSAGE (mean aggr), N=100000 nodes, E=600000 edges.
// DIMS: 128 -> 64 -> 32 -> 16 -> 9.
//
// Key restructure: mean-aggregation is linear, so agg(x) @ w_l == agg(x @ w_l).
// Per layer:
//   lin:  y = x @ w_l          [N, fout]
//         z = x @ w_r + b      -> written straight into the layer-output buffer
//   agg:  out[n] = act(z[n] + (sum_{e in in-edges(n)} y[src_e]) / max(deg_n,1))
// Aggregation is pull-style over a CSR (built on-device each launch):
// no float atomics, coalesced gathers of fout-wide rows.

#define BLK 256

// ---------------- CSR build ----------------

__global__ void hist_kernel(const int* __restrict__ dst, int* __restrict__ deg, int e) {
    int t = blockIdx.x * blockDim.x + threadIdx.x;
    if (t < e) atomicAdd(&deg[dst[t]], 1);
}

// Each block scans a 1024-element chunk (256 threads x 4), writes local exclusive
// scan into row_start and the chunk total into bsums[blockIdx].
__global__ void scan1_kernel(const int* __restrict__ deg, int* __restrict__ excl,
                             int* __restrict__ bsums, int n) {
    __shared__ int sm[256];
    int base = blockIdx.x * 1024;
    int t = threadIdx.x;
    int v[4];
    int s = 0;
    #pragma unroll
    for (int j = 0; j < 4; j++) {
        int i = base + t * 4 + j;
        v[j] = (i < n) ? deg[i] : 0;
        s += v[j];
    }
    sm[t] = s;
    __syncthreads();
    for (int off = 1; off < 256; off <<= 1) {
        int x = (t >= off) ? sm[t - off] : 0;
        __syncthreads();
        sm[t] += x;
        __syncthreads();
    }
    int excl_t = sm[t] - s;           // exclusive prefix within chunk
    if (t == 255) bsums[blockIdx.x] = sm[255];
    int run = excl_t;
    #pragma unroll
    for (int j = 0; j < 4; j++) {
        int i = base + t * 4 + j;
        if (i < n) excl[i] = run;
        run += v[j];
    }
}

// Single block: exclusive scan of chunk totals (nb <= 256; nb = ceil(1e5/1024) = 98).
__global__ void scan2_kernel(int* __restrict__ bsums, int nb) {
    __shared__ int sm[256];
    int t = threadIdx.x;
    int v = (t < nb) ? bsums[t] : 0;
    sm[t] = v;
    __syncthreads();
    for (int off = 1; off < 256; off <<= 1) {
        int x = (t >= off) ? sm[t - off] : 0;
        __syncthreads();
        sm[t] += x;
        __syncthreads();
    }
    if (t < nb) bsums[t] = sm[t] - v;  // exclusive
}

__global__ void scan3_kernel(const int* __restrict__ deg, int* __restrict__ row_start,
                             const int* __restrict__ bsums, int* __restrict__ cursor,
                             float* __restrict__ inv_deg, int n, int e) {
    int t = blockIdx.x * blockDim.x + threadIdx.x;
    if (t < n) {
        int rs = row_start[t] + bsums[t >> 10];
        row_start[t] = rs;
        cursor[t] = rs;
        int d = deg[t];
        inv_deg[t] = 1.0f / (float)(d > 1 ? d : 1);
    }
    if (t == 0) row_start[n] = e;
}

__global__ void scatter_kernel(const int* __restrict__ src, const int* __restrict__ dst,
                               int* __restrict__ cursor, int* __restrict__ ssrc, int e) {
    int t = blockIdx.x * blockDim.x + threadIdx.x;
    if (t < e) {
        int p = atomicAdd(&cursor[dst[t]], 1);
        ssrc[p] = src[t];
    }
}

// ---------------- per-layer kernels ----------------

// y[n][f] = sum_k x[n][k] * wl[k][f]
// z[n][f] = sum_k x[n][k] * wr[k][f] + b[f]   (z written into the layer output buffer)
template <int FIN, int FOUT>
__global__ void lin_kernel(const float* __restrict__ x, const float* __restrict__ wl,
                           const float* __restrict__ wr, const float* __restrict__ b,
                           float* __restrict__ y, float* __restrict__ z, int n) {
    int t = blockIdx.x * blockDim.x + threadIdx.x;
    int node = t / FOUT;
    int f = t % FOUT;
    if (node >= n) return;
    const float* xr = x + (size_t)node * FIN;
    float accy = 0.f, accz = 0.f;
    #pragma unroll 8
    for (int k = 0; k < FIN; k++) {
        float xv = xr[k];                    // wave-uniform (FOUT>=32): broadcast
        accy = fmaf(xv, wl[k * FOUT + f], accy);   // coalesced, L1-resident weights
        accz = fmaf(xv, wr[k * FOUT + f], accz);
    }
    y[(size_t)node * FOUT + f] = accy;
    z[(size_t)node * FOUT + f] = accz + b[f];
}

// out[n][f] = act(out[n][f] + (sum_{e} y[ssrc[e]][f]) * inv_deg[n])
template <int FOUT, bool RELU>
__global__ void agg_kernel(const float* __restrict__ y, const int* __restrict__ row_start,
                           const int* __restrict__ ssrc, const float* __restrict__ inv_deg,
                           float* __restrict__ out, int n) {
    int t = blockIdx.x * blockDim.x + threadIdx.x;
    int node = t / FOUT;
    int f = t % FOUT;
    if (node >= n) return;
    int e0 = row_start[node];
    int e1 = row_start[node + 1];
    float s = 0.f;
    for (int e = e0; e < e1; e++) {
        int sn = ssrc[e];                    // wave-uniform-ish broadcast
        s += y[(size_t)sn * FOUT + f];       // coalesced FOUT-wide row gather
    }
    float v = out[(size_t)node * FOUT + f] + s * inv_deg[node];
    if (RELU) v = fmaxf(v, 0.f);
    out[(size_t)node * FOUT + f] = v;
}

// ---------------- launch ----------------

static inline int cdiv(int a, int b) { return (a + b - 1) / b; }

extern "C" void kernel_launch(void* const* d_in, const int* in_sizes, int n_in,
                              void* d_out, int out_size, void* d_ws, size_t ws_size,
                              hipStream_t stream) {
    const float* emb  = (const float*)d_in[0];
    const int*   eidx = (const int*)d_in[1];
    // d_in[2] = edge_attr (unused by SAGEConv)
    const float* wl0 = (const float*)d_in[3];
    const float* wr0 = (const float*)d_in[4];
    const float* b0  = (const float*)d_in[5];
    const float* wl1 = (const float*)d_in[6];
    const float* wr1 = (const float*)d_in[7];
    const float* b1  = (const float*)d_in[8];
    const float* wl2 = (const float*)d_in[9];
    const float* wr2 = (const float*)d_in[10];
    const float* b2  = (const float*)d_in[11];
    const float* wl3 = (const float*)d_in[12];
    const float* wr3 = (const float*)d_in[13];
    const float* b3  = (const float*)d_in[14];

    const int n = in_sizes[0] / 128;   // 100000
    const int e = in_sizes[1] / 2;     // 600000
    const int* src = eidx;             // edge_index[0]
    const int* dst = eidx + e;         // edge_index[1]

    // workspace carve-up (256B aligned): ~68 MB total
    char* ws = (char*)d_ws;
    size_t off = 0;
    auto alloc = [&](size_t bytes) -> void* {
        void* p = ws + off;
        off = (off + bytes + 255) & ~(size_t)255;
        return p;
    };
    int*   deg       = (int*)alloc((size_t)n * 4);
    float* inv_deg   = (float*)alloc((size_t)n * 4);
    int*   row_start = (int*)alloc(((size_t)n + 1) * 4);
    int*   cursor    = (int*)alloc((size_t)n * 4);
    int*   bsums     = (int*)alloc(1024 * 4);
    int*   ssrc      = (int*)alloc((size_t)e * 4);
    float* Y         = (float*)alloc((size_t)n * 64 * 4);
    float* xA        = (float*)alloc((size_t)n * 64 * 4);
    float* xB        = (float*)alloc((size_t)n * 32 * 4);
    (void)ws_size;

    // ---- CSR build ----
    hipMemsetAsync(deg, 0, (size_t)n * 4, stream);
    hist_kernel<<<cdiv(e, BLK), BLK, 0, stream>>>(dst, deg, e);
    int nchunks = cdiv(n, 1024);  // 98 <= 256
    scan1_kernel<<<nchunks, 256, 0, stream>>>(deg, row_start, bsums, n);
    scan2_kernel<<<1, 256, 0, stream>>>(bsums, nchunks);
    scan3_kernel<<<cdiv(n, BLK), BLK, 0, stream>>>(deg, row_start, bsums, cursor, inv_deg, n, e);
    scatter_kernel<<<cdiv(e, BLK), BLK, 0, stream>>>(src, dst, cursor, ssrc, e);

    float* out = (float*)d_out;

    // ---- layer 0: 128 -> 64, relu, x_in=emb, out=xA ----
    lin_kernel<128, 64><<<cdiv(n * 64, BLK), BLK, 0, stream>>>(emb, wl0, wr0, b0, Y, xA, n);
    agg_kernel<64, true><<<cdiv(n * 64, BLK), BLK, 0, stream>>>(Y, row_start, ssrc, inv_deg, xA, n);

    // ---- layer 1: 64 -> 32, relu, x_in=xA, out=xB ----
    lin_kernel<64, 32><<<cdiv(n * 32, BLK), BLK, 0, stream>>>(xA, wl1, wr1, b1, Y, xB, n);
    agg_kernel<32, true><<<cdiv(n * 32, BLK), BLK, 0, stream>>>(Y, row_start, ssrc, inv_deg, xB, n);

    // ---- layer 2: 32 -> 16, relu, x_in=xB, out=xA (reuse) ----
    lin_kernel<32, 16><<<cdiv(n * 16, BLK), BLK, 0, stream>>>(xB, wl2, wr2, b2, Y, xA, n);
    agg_kernel<16, true><<<cdiv(n * 16, BLK), BLK, 0, stream>>>(Y, row_start, ssrc, inv_deg, xA, n);

    // ---- layer 3: 16 -> 9, no relu, x_in=xA, out=d_out ----
    lin_kernel<16, 9><<<cdiv(n * 9, BLK), BLK, 0, stream>>>(xA, wl3, wr3, b3, Y, out, n);
    agg_kernel<9, false><<<cdiv(n * 9, BLK), BLK, 0, stream>>>(Y, row_start, ssrc, inv_deg, out, n);
}

// Round 3
// 600.859 us; speedup vs baseline: 1.1718x; 1.1718x over previous
//
#include <hip/hip_runtime.h>
#include <hip/hip_bf16.h>

// SageNet: 4-layer GraphSAGE (mean aggr), N=100000 nodes, E=600000 edges.
// DIMS: 128 -> 64 -> 32 -> 16 -> 9.
//
// agg(x) @ w_l == agg(x @ w_l)  (mean aggregation is linear), so per layer:
//   lin:  y = x @ w_l ; z = x @ w_r + b   (tiled dual-GEMM, shared A-fragments)
//   agg:  out[n] = act(z[n] + (sum_{in-edges} y[src]) * inv_deg[n])
// Pull-style CSR aggregation (built on device), zero float atomics.

#define BLK 256

// ---------------- CSR build ----------------

__global__ void hist_kernel(const int* __restrict__ dst, int* __restrict__ deg, int e) {
    int t = blockIdx.x * blockDim.x + threadIdx.x;
    if (t < e) atomicAdd(&deg[dst[t]], 1);
}

__global__ void scan1_kernel(const int* __restrict__ deg, int* __restrict__ excl,
                             int* __restrict__ bsums, int n) {
    __shared__ int sm[256];
    int base = blockIdx.x * 1024;
    int t = threadIdx.x;
    int v[4];
    int s = 0;
    #pragma unroll
    for (int j = 0; j < 4; j++) {
        int i = base + t * 4 + j;
        v[j] = (i < n) ? deg[i] : 0;
        s += v[j];
    }
    sm[t] = s;
    __syncthreads();
    for (int off = 1; off < 256; off <<= 1) {
        int x = (t >= off) ? sm[t - off] : 0;
        __syncthreads();
        sm[t] += x;
        __syncthreads();
    }
    int excl_t = sm[t] - s;
    if (t == 255) bsums[blockIdx.x] = sm[255];
    int run = excl_t;
    #pragma unroll
    for (int j = 0; j < 4; j++) {
        int i = base + t * 4 + j;
        if (i < n) excl[i] = run;
        run += v[j];
    }
}

__global__ void scan2_kernel(int* __restrict__ bsums, int nb) {
    __shared__ int sm[256];
    int t = threadIdx.x;
    int v = (t < nb) ? bsums[t] : 0;
    sm[t] = v;
    __syncthreads();
    for (int off = 1; off < 256; off <<= 1) {
        int x = (t >= off) ? sm[t - off] : 0;
        __syncthreads();
        sm[t] += x;
        __syncthreads();
    }
    if (t < nb) bsums[t] = sm[t] - v;
}

__global__ void scan3_kernel(const int* __restrict__ deg, int* __restrict__ row_start,
                             const int* __restrict__ bsums, int* __restrict__ cursor,
                             float* __restrict__ inv_deg, int n, int e) {
    int t = blockIdx.x * blockDim.x + threadIdx.x;
    if (t < n) {
        int rs = row_start[t] + bsums[t >> 10];
        row_start[t] = rs;
        cursor[t] = rs;
        int d = deg[t];
        inv_deg[t] = 1.0f / (float)(d > 1 ? d : 1);
    }
    if (t == 0) row_start[n] = e;
}

__global__ void scatter_kernel(const int* __restrict__ src, const int* __restrict__ dst,
                               int* __restrict__ cursor, int* __restrict__ ssrc, int e) {
    int t = blockIdx.x * blockDim.x + threadIdx.x;
    if (t < e) {
        int p = atomicAdd(&cursor[dst[t]], 1);
        ssrc[p] = src[t];
    }
}

// ---------------- tiled dual-GEMM lin ----------------
// y = x @ wl ; z = x @ wr + b.  BM nodes x BN=FOUT cols per block; KC k-chunk.
// Thread tile TM x TN, both accumulators share the same A fragment.

template <int FIN, int FOUT, int BM, int KC, int TM, int TN>
__global__ void lin_tiled(const float* __restrict__ x, const float* __restrict__ wl,
                          const float* __restrict__ wr, const float* __restrict__ b,
                          float* __restrict__ y, float* __restrict__ z, int n) {
    constexpr int BN = FOUT;
    constexpr int THREADS = (BM / TM) * (BN / TN);
    constexpr int PAD = 4;                       // keep rows 16B-aligned, banks spread
    __shared__ float xT[KC][BM + PAD];           // transposed x tile
    __shared__ float wls[KC][BN];
    __shared__ float wrs[KC][BN];

    const int tid = threadIdx.x;
    const int r = tid / (BN / TN);
    const int c = tid % (BN / TN);
    const int m0 = r * TM;
    const int f0 = c * TN;
    const int nodeBase = blockIdx.x * BM;

    float accy[TM][TN] = {};
    float accz[TM][TN] = {};

    for (int k0 = 0; k0 < FIN; k0 += KC) {
        // stage x^T (coalesced float4 global reads, scalar transposed LDS writes)
        constexpr int XLOADS = (BM * KC) / (THREADS * 4);
        #pragma unroll
        for (int l = 0; l < XLOADS; l++) {
            int idx = (l * THREADS + tid) * 4;
            int node = idx / KC;
            int kk = idx % KC;
            float4 v = {0.f, 0.f, 0.f, 0.f};
            int gn = nodeBase + node;
            if (gn < n) v = *(const float4*)(x + (size_t)gn * FIN + k0 + kk);
            xT[kk + 0][node] = v.x;
            xT[kk + 1][node] = v.y;
            xT[kk + 2][node] = v.z;
            xT[kk + 3][node] = v.w;
        }
        // stage weights (chunk rows are contiguous in global)
        constexpr int WLOADS = (KC * BN) / (THREADS * 4);
        #pragma unroll
        for (int l = 0; l < WLOADS; l++) {
            int idx = (l * THREADS + tid) * 4;
            *(float4*)(&wls[0][0] + idx) = *(const float4*)(wl + (size_t)k0 * FOUT + idx);
            *(float4*)(&wrs[0][0] + idx) = *(const float4*)(wr + (size_t)k0 * FOUT + idx);
        }
        __syncthreads();

        #pragma unroll
        for (int k = 0; k < KC; k++) {
            float a[TM], bl[TN], br[TN];
            #pragma unroll
            for (int i = 0; i < TM; i += 4) *(float4*)&a[i] = *(const float4*)&xT[k][m0 + i];
            #pragma unroll
            for (int j = 0; j < TN; j += 4) {
                *(float4*)&bl[j] = *(const float4*)&wls[k][f0 + j];
                *(float4*)&br[j] = *(const float4*)&wrs[k][f0 + j];
            }
            #pragma unroll
            for (int i = 0; i < TM; i++)
                #pragma unroll
                for (int j = 0; j < TN; j++) {
                    accy[i][j] = fmaf(a[i], bl[j], accy[i][j]);
                    accz[i][j] = fmaf(a[i], br[j], accz[i][j]);
                }
        }
        __syncthreads();
    }

    // epilogue: y, z(+bias) as float4 stores
    float bias[TN];
    #pragma unroll
    for (int j = 0; j < TN; j++) bias[j] = b[f0 + j];
    #pragma unroll
    for (int i = 0; i < TM; i++) {
        int gn = nodeBase + m0 + i;
        if (gn < n) {
            #pragma unroll
            for (int j = 0; j < TN; j += 4) {
                float4 vy = {accy[i][j], accy[i][j+1], accy[i][j+2], accy[i][j+3]};
                float4 vz = {accz[i][j] + bias[j], accz[i][j+1] + bias[j+1],
                             accz[i][j+2] + bias[j+2], accz[i][j+3] + bias[j+3]};
                *(float4*)(y + (size_t)gn * FOUT + f0 + j) = vy;
                *(float4*)(z + (size_t)gn * FOUT + f0 + j) = vz;
            }
        }
    }
}

// naive lin for the tiny last layer (16 -> 9)
template <int FIN, int FOUT>
__global__ void lin_naive(const float* __restrict__ x, const float* __restrict__ wl,
                          const float* __restrict__ wr, const float* __restrict__ b,
                          float* __restrict__ y, float* __restrict__ z, int n) {
    int t = blockIdx.x * blockDim.x + threadIdx.x;
    int node = t / FOUT;
    int f = t % FOUT;
    if (node >= n) return;
    const float* xr = x + (size_t)node * FIN;
    float accy = 0.f, accz = 0.f;
    #pragma unroll
    for (int k = 0; k < FIN; k++) {
        float xv = xr[k];
        accy = fmaf(xv, wl[k * FOUT + f], accy);
        accz = fmaf(xv, wr[k * FOUT + f], accz);
    }
    y[(size_t)node * FOUT + f] = accy;
    z[(size_t)node * FOUT + f] = accz + b[f];
}

// ---------------- aggregation ----------------

// float4 version: thread owns 4 consecutive f of one node
template <int FOUT, bool RELU>
__global__ void agg4_kernel(const float4* __restrict__ y4, const int* __restrict__ row_start,
                            const int* __restrict__ ssrc, const float* __restrict__ inv_deg,
                            float4* __restrict__ out4, int n) {
    constexpr int Q = FOUT / 4;
    int t = blockIdx.x * blockDim.x + threadIdx.x;
    int node = t / Q;
    int q = t % Q;
    if (node >= n) return;
    int e0 = row_start[node];
    int e1 = row_start[node + 1];
    float4 s = {0.f, 0.f, 0.f, 0.f};
    for (int e = e0; e < e1; e++) {
        int sn = ssrc[e];
        float4 v = y4[(size_t)sn * Q + q];
        s.x += v.x; s.y += v.y; s.z += v.z; s.w += v.w;
    }
    float id = inv_deg[node];
    float4 o = out4[(size_t)node * Q + q];
    o.x += s.x * id; o.y += s.y * id; o.z += s.z * id; o.w += s.w * id;
    if (RELU) {
        o.x = fmaxf(o.x, 0.f); o.y = fmaxf(o.y, 0.f);
        o.z = fmaxf(o.z, 0.f); o.w = fmaxf(o.w, 0.f);
    }
    out4[(size_t)node * Q + q] = o;
}

// scalar version for FOUT=9
template <int FOUT, bool RELU>
__global__ void agg_kernel(const float* __restrict__ y, const int* __restrict__ row_start,
                           const int* __restrict__ ssrc, const float* __restrict__ inv_deg,
                           float* __restrict__ out, int n) {
    int t = blockIdx.x * blockDim.x + threadIdx.x;
    int node = t / FOUT;
    int f = t % FOUT;
    if (node >= n) return;
    int e0 = row_start[node];
    int e1 = row_start[node + 1];
    float s = 0.f;
    for (int e = e0; e < e1; e++) {
        int sn = ssrc[e];
        s += y[(size_t)sn * FOUT + f];
    }
    float v = out[(size_t)node * FOUT + f] + s * inv_deg[node];
    if (RELU) v = fmaxf(v, 0.f);
    out[(size_t)node * FOUT + f] = v;
}

// ---------------- launch ----------------

static inline int cdiv(int a, int b) { return (a + b - 1) / b; }

extern "C" void kernel_launch(void* const* d_in, const int* in_sizes, int n_in,
                              void* d_out, int out_size, void* d_ws, size_t ws_size,
                              hipStream_t stream) {
    const float* emb  = (const float*)d_in[0];
    const int*   eidx = (const int*)d_in[1];
    const float* wl0 = (const float*)d_in[3];
    const float* wr0 = (const float*)d_in[4];
    const float* b0  = (const float*)d_in[5];
    const float* wl1 = (const float*)d_in[6];
    const float* wr1 = (const float*)d_in[7];
    const float* b1  = (const float*)d_in[8];
    const float* wl2 = (const float*)d_in[9];
    const float* wr2 = (const float*)d_in[10];
    const float* b2  = (const float*)d_in[11];
    const float* wl3 = (const float*)d_in[12];
    const float* wr3 = (const float*)d_in[13];
    const float* b3  = (const float*)d_in[14];

    const int n = in_sizes[0] / 128;   // 100000
    const int e = in_sizes[1] / 2;     // 600000
    const int* src = eidx;
    const int* dst = eidx + e;

    char* ws = (char*)d_ws;
    size_t off = 0;
    auto alloc = [&](size_t bytes) -> void* {
        void* p = ws + off;
        off = (off + bytes + 255) & ~(size_t)255;
        return p;
    };
    int*   deg       = (int*)alloc((size_t)n * 4);
    float* inv_deg   = (float*)alloc((size_t)n * 4);
    int*   row_start = (int*)alloc(((size_t)n + 1) * 4);
    int*   cursor    = (int*)alloc((size_t)n * 4);
    int*   bsums     = (int*)alloc(1024 * 4);
    int*   ssrc      = (int*)alloc((size_t)e * 4);
    float* Y         = (float*)alloc((size_t)n * 64 * 4);
    float* xA        = (float*)alloc((size_t)n * 64 * 4);
    float* xB        = (float*)alloc((size_t)n * 32 * 4);
    (void)ws_size;

    // ---- CSR build ----
    hipMemsetAsync(deg, 0, (size_t)n * 4, stream);
    hist_kernel<<<cdiv(e, BLK), BLK, 0, stream>>>(dst, deg, e);
    int nchunks = cdiv(n, 1024);
    scan1_kernel<<<nchunks, 256, 0, stream>>>(deg, row_start, bsums, n);
    scan2_kernel<<<1, 256, 0, stream>>>(bsums, nchunks);
    scan3_kernel<<<cdiv(n, BLK), BLK, 0, stream>>>(deg, row_start, bsums, cursor, inv_deg, n, e);
    scatter_kernel<<<cdiv(e, BLK), BLK, 0, stream>>>(src, dst, cursor, ssrc, e);

    float* out = (float*)d_out;

    // ---- layer 0: 128 -> 64, relu ----
    // BM=128, KC=32, TM=8, TN=4 -> 256 threads
    lin_tiled<128, 64, 128, 32, 8, 4><<<cdiv(n, 128), 256, 0, stream>>>(emb, wl0, wr0, b0, Y, xA, n);
    agg4_kernel<64, true><<<cdiv(n * 16, BLK), BLK, 0, stream>>>((const float4*)Y, row_start, ssrc, inv_deg, (float4*)xA, n);

    // ---- layer 1: 64 -> 32, relu ----  128 threads
    lin_tiled<64, 32, 128, 32, 8, 4><<<cdiv(n, 128), 128, 0, stream>>>(xA, wl1, wr1, b1, Y, xB, n);
    agg4_kernel<32, true><<<cdiv(n * 8, BLK), BLK, 0, stream>>>((const float4*)Y, row_start, ssrc, inv_deg, (float4*)xB, n);

    // ---- layer 2: 32 -> 16, relu ----  BM=256 -> 128 threads
    lin_tiled<32, 16, 256, 32, 8, 4><<<cdiv(n, 256), 128, 0, stream>>>(xB, wl2, wr2, b2, Y, xA, n);
    agg4_kernel<16, true><<<cdiv(n * 4, BLK), BLK, 0, stream>>>((const float4*)Y, row_start, ssrc, inv_deg, (float4*)xA, n);

    // ---- layer 3: 16 -> 9, no relu ----
    lin_naive<16, 9><<<cdiv(n * 9, BLK), BLK, 0, stream>>>(xA, wl3, wr3, b3, Y, out, n);
    agg_kernel<9, false><<<cdiv(n * 9, BLK), BLK, 0, stream>>>(Y, row_start, ssrc, inv_deg, out, n);
}

// Round 6
// 425.916 us; speedup vs baseline: 1.6531x; 1.4107x over previous
//
#include <hip/hip_runtime.h>
#include <hip/hip_bf16.h>

// SageNet: 4-layer GraphSAGE (mean aggr), N=100000 nodes, E=600000 edges.
// DIMS: 128 -> 64 -> 32 -> 16 -> 9.
//
// agg(x) @ w_l == agg(x @ w_l)  (mean aggregation is linear), so per layer:
//   lin:  y = x @ wl ; z = x @ wr + b   (layers 0-1: tiled dual-GEMM;
//                                        layers 2-3: naive per-node, tiny work)
//   agg:  out[n] = act(z[n] + (sum_{in-edges} y[src]) * inv_deg[n])
// Pull-style CSR aggregation (built on device), zero float atomics.
//
// R3 lesson: lin_tiled<32,16,BM=256> showed 203us with impossible 317MB FETCH
// (input is 12.8MB). Removed that kernel class for tiny layers; naive lin was
// measured in R1 and scales to ~20us here.

#define BLK 256

// ---------------- CSR build ----------------

__global__ void hist_kernel(const int* __restrict__ dst, int* __restrict__ deg, int e) {
    int t = blockIdx.x * blockDim.x + threadIdx.x;
    if (t < e) atomicAdd(&deg[dst[t]], 1);
}

__global__ void scan1_kernel(const int* __restrict__ deg, int* __restrict__ excl,
                             int* __restrict__ bsums, int n) {
    __shared__ int sm[256];
    int base = blockIdx.x * 1024;
    int t = threadIdx.x;
    int v[4];
    int s = 0;
    #pragma unroll
    for (int j = 0; j < 4; j++) {
        int i = base + t * 4 + j;
        v[j] = (i < n) ? deg[i] : 0;
        s += v[j];
    }
    sm[t] = s;
    __syncthreads();
    for (int off = 1; off < 256; off <<= 1) {
        int x = (t >= off) ? sm[t - off] : 0;
        __syncthreads();
        sm[t] += x;
        __syncthreads();
    }
    int excl_t = sm[t] - s;
    if (t == 255) bsums[blockIdx.x] = sm[255];
    int run = excl_t;
    #pragma unroll
    for (int j = 0; j < 4; j++) {
        int i = base + t * 4 + j;
        if (i < n) excl[i] = run;
        run += v[j];
    }
}

__global__ void scan2_kernel(int* __restrict__ bsums, int nb) {
    __shared__ int sm[256];
    int t = threadIdx.x;
    int v = (t < nb) ? bsums[t] : 0;
    sm[t] = v;
    __syncthreads();
    for (int off = 1; off < 256; off <<= 1) {
        int x = (t >= off) ? sm[t - off] : 0;
        __syncthreads();
        sm[t] += x;
        __syncthreads();
    }
    if (t < nb) bsums[t] = sm[t] - v;
}

__global__ void scan3_kernel(const int* __restrict__ deg, int* __restrict__ row_start,
                             const int* __restrict__ bsums, int* __restrict__ cursor,
                             float* __restrict__ inv_deg, int n, int e) {
    int t = blockIdx.x * blockDim.x + threadIdx.x;
    if (t < n) {
        int rs = row_start[t] + bsums[t >> 10];
        row_start[t] = rs;
        cursor[t] = rs;
        int d = deg[t];
        inv_deg[t] = 1.0f / (float)(d > 1 ? d : 1);
    }
    if (t == 0) row_start[n] = e;
}

__global__ void scatter_kernel(const int* __restrict__ src, const int* __restrict__ dst,
                               int* __restrict__ cursor, int* __restrict__ ssrc, int e) {
    int t = blockIdx.x * blockDim.x + threadIdx.x;
    if (t < e) {
        int p = atomicAdd(&cursor[dst[t]], 1);
        ssrc[p] = src[t];
    }
}

// ---------------- tiled dual-GEMM lin (layers 0-1) ----------------
// y = x @ wl ; z = x @ wr + b.  BM nodes x BN=FOUT cols per block; KC k-chunk.

template <int FIN, int FOUT, int BM, int KC, int TM, int TN>
__global__ void lin_tiled(const float* __restrict__ x, const float* __restrict__ wl,
                          const float* __restrict__ wr, const float* __restrict__ b,
                          float* __restrict__ y, float* __restrict__ z, int n) {
    constexpr int BN = FOUT;
    constexpr int THREADS = (BM / TM) * (BN / TN);
    constexpr int PAD = 4;
    __shared__ float xT[KC][BM + PAD];
    __shared__ float wls[KC][BN];
    __shared__ float wrs[KC][BN];

    const int tid = threadIdx.x;
    const int r = tid / (BN / TN);
    const int c = tid % (BN / TN);
    const int m0 = r * TM;
    const int f0 = c * TN;
    const int nodeBase = blockIdx.x * BM;

    float accy[TM][TN] = {};
    float accz[TM][TN] = {};

    for (int k0 = 0; k0 < FIN; k0 += KC) {
        constexpr int XLOADS = (BM * KC) / (THREADS * 4);
        #pragma unroll
        for (int l = 0; l < XLOADS; l++) {
            int idx = (l * THREADS + tid) * 4;
            int node = idx / KC;
            int kk = idx % KC;
            float4 v = {0.f, 0.f, 0.f, 0.f};
            int gn = nodeBase + node;
            if (gn < n) v = *(const float4*)(x + (size_t)gn * FIN + k0 + kk);
            xT[kk + 0][node] = v.x;
            xT[kk + 1][node] = v.y;
            xT[kk + 2][node] = v.z;
            xT[kk + 3][node] = v.w;
        }
        constexpr int WLOADS = (KC * BN) / (THREADS * 4);
        #pragma unroll
        for (int l = 0; l < WLOADS; l++) {
            int idx = (l * THREADS + tid) * 4;
            *(float4*)(&wls[0][0] + idx) = *(const float4*)(wl + (size_t)k0 * FOUT + idx);
            *(float4*)(&wrs[0][0] + idx) = *(const float4*)(wr + (size_t)k0 * FOUT + idx);
        }
        __syncthreads();

        #pragma unroll
        for (int k = 0; k < KC; k++) {
            float a[TM], bl[TN], br[TN];
            #pragma unroll
            for (int i = 0; i < TM; i += 4) *(float4*)&a[i] = *(const float4*)&xT[k][m0 + i];
            #pragma unroll
            for (int j = 0; j < TN; j += 4) {
                *(float4*)&bl[j] = *(const float4*)&wls[k][f0 + j];
                *(float4*)&br[j] = *(const float4*)&wrs[k][f0 + j];
            }
            #pragma unroll
            for (int i = 0; i < TM; i++)
                #pragma unroll
                for (int j = 0; j < TN; j++) {
                    accy[i][j] = fmaf(a[i], bl[j], accy[i][j]);
                    accz[i][j] = fmaf(a[i], br[j], accz[i][j]);
                }
        }
        __syncthreads();
    }

    float bias[TN];
    #pragma unroll
    for (int j = 0; j < TN; j++) bias[j] = b[f0 + j];
    #pragma unroll
    for (int i = 0; i < TM; i++) {
        int gn = nodeBase + m0 + i;
        if (gn < n) {
            #pragma unroll
            for (int j = 0; j < TN; j += 4) {
                float4 vy = {accy[i][j], accy[i][j+1], accy[i][j+2], accy[i][j+3]};
                float4 vz = {accz[i][j] + bias[j], accz[i][j+1] + bias[j+1],
                             accz[i][j+2] + bias[j+2], accz[i][j+3] + bias[j+3]};
                *(float4*)(y + (size_t)gn * FOUT + f0 + j) = vy;
                *(float4*)(z + (size_t)gn * FOUT + f0 + j) = vz;
            }
        }
    }
}

// naive per-node lin for the tiny layers (2: 32->16, 3: 16->9).
// R1 measured this class: layer-0-sized = 315us -> layer2 ~1/16 work ~20us.
template <int FIN, int FOUT>
__global__ void lin_naive(const float* __restrict__ x, const float* __restrict__ wl,
                          const float* __restrict__ wr, const float* __restrict__ b,
                          float* __restrict__ y, float* __restrict__ z, int n) {
    int t = blockIdx.x * blockDim.x + threadIdx.x;
    int node = t / FOUT;
    int f = t % FOUT;
    if (node >= n) return;
    const float* xr = x + (size_t)node * FIN;
    float accy = 0.f, accz = 0.f;
    #pragma unroll
    for (int k = 0; k < FIN; k++) {
        float xv = xr[k];
        accy = fmaf(xv, wl[k * FOUT + f], accy);
        accz = fmaf(xv, wr[k * FOUT + f], accz);
    }
    y[(size_t)node * FOUT + f] = accy;
    z[(size_t)node * FOUT + f] = accz + b[f];
}

// ---------------- aggregation ----------------

template <int FOUT, bool RELU>
__global__ void agg4_kernel(const float4* __restrict__ y4, const int* __restrict__ row_start,
                            const int* __restrict__ ssrc, const float* __restrict__ inv_deg,
                            float4* __restrict__ out4, int n) {
    constexpr int Q = FOUT / 4;
    int t = blockIdx.x * blockDim.x + threadIdx.x;
    int node = t / Q;
    int q = t % Q;
    if (node >= n) return;
    int e0 = row_start[node];
    int e1 = row_start[node + 1];
    float4 s = {0.f, 0.f, 0.f, 0.f};
    for (int e = e0; e < e1; e++) {
        int sn = ssrc[e];
        float4 v = y4[(size_t)sn * Q + q];
        s.x += v.x; s.y += v.y; s.z += v.z; s.w += v.w;
    }
    float id = inv_deg[node];
    float4 o = out4[(size_t)node * Q + q];
    o.x += s.x * id; o.y += s.y * id; o.z += s.z * id; o.w += s.w * id;
    if (RELU) {
        o.x = fmaxf(o.x, 0.f); o.y = fmaxf(o.y, 0.f);
        o.z = fmaxf(o.z, 0.f); o.w = fmaxf(o.w, 0.f);
    }
    out4[(size_t)node * Q + q] = o;
}

template <int FOUT, bool RELU>
__global__ void agg_kernel(const float* __restrict__ y, const int* __restrict__ row_start,
                           const int* __restrict__ ssrc, const float* __restrict__ inv_deg,
                           float* __restrict__ out, int n) {
    int t = blockIdx.x * blockDim.x + threadIdx.x;
    int node = t / FOUT;
    int f = t % FOUT;
    if (node >= n) return;
    int e0 = row_start[node];
    int e1 = row_start[node + 1];
    float s = 0.f;
    for (int e = e0; e < e1; e++) {
        int sn = ssrc[e];
        s += y[(size_t)sn * FOUT + f];
    }
    float v = out[(size_t)node * FOUT + f] + s * inv_deg[node];
    if (RELU) v = fmaxf(v, 0.f);
    out[(size_t)node * FOUT + f] = v;
}

// ---------------- launch ----------------

static inline int cdiv(int a, int b) { return (a + b - 1) / b; }

extern "C" void kernel_launch(void* const* d_in, const int* in_sizes, int n_in,
                              void* d_out, int out_size, void* d_ws, size_t ws_size,
                              hipStream_t stream) {
    const float* emb  = (const float*)d_in[0];
    const int*   eidx = (const int*)d_in[1];
    const float* wl0 = (const float*)d_in[3];
    const float* wr0 = (const float*)d_in[4];
    const float* b0  = (const float*)d_in[5];
    const float* wl1 = (const float*)d_in[6];
    const float* wr1 = (const float*)d_in[7];
    const float* b1  = (const float*)d_in[8];
    const float* wl2 = (const float*)d_in[9];
    const float* wr2 = (const float*)d_in[10];
    const float* b2  = (const float*)d_in[11];
    const float* wl3 = (const float*)d_in[12];
    const float* wr3 = (const float*)d_in[13];
    const float* b3  = (const float*)d_in[14];

    const int n = in_sizes[0] / 128;   // 100000
    const int e = in_sizes[1] / 2;     // 600000
    const int* src = eidx;
    const int* dst = eidx + e;

    char* ws = (char*)d_ws;
    size_t off = 0;
    auto alloc = [&](size_t bytes) -> void* {
        void* p = ws + off;
        off = (off + bytes + 255) & ~(size_t)255;
        return p;
    };
    int*   deg       = (int*)alloc((size_t)n * 4);
    float* inv_deg   = (float*)alloc((size_t)n * 4);
    int*   row_start = (int*)alloc(((size_t)n + 1) * 4);
    int*   cursor    = (int*)alloc((size_t)n * 4);
    int*   bsums     = (int*)alloc(1024 * 4);
    int*   ssrc      = (int*)alloc((size_t)e * 4);
    float* Y         = (float*)alloc((size_t)n * 64 * 4);
    float* xA        = (float*)alloc((size_t)n * 64 * 4);
    float* xB        = (float*)alloc((size_t)n * 32 * 4);
    (void)ws_size;

    // ---- CSR build ----
    hipMemsetAsync(deg, 0, (size_t)n * 4, stream);
    hist_kernel<<<cdiv(e, BLK), BLK, 0, stream>>>(dst, deg, e);
    int nchunks = cdiv(n, 1024);
    scan1_kernel<<<nchunks, 256, 0, stream>>>(deg, row_start, bsums, n);
    scan2_kernel<<<1, 256, 0, stream>>>(bsums, nchunks);
    scan3_kernel<<<cdiv(n, BLK), BLK, 0, stream>>>(deg, row_start, bsums, cursor, inv_deg, n, e);
    scatter_kernel<<<cdiv(e, BLK), BLK, 0, stream>>>(src, dst, cursor, ssrc, e);

    float* out = (float*)d_out;

    // ---- layer 0: 128 -> 64, relu ----  BM=128, 256 threads
    lin_tiled<128, 64, 128, 32, 8, 4><<<cdiv(n, 128), 256, 0, stream>>>(emb, wl0, wr0, b0, Y, xA, n);
    agg4_kernel<64, true><<<cdiv(n * 16, BLK), BLK, 0, stream>>>((const float4*)Y, row_start, ssrc, inv_deg, (float4*)xA, n);

    // ---- layer 1: 64 -> 32, relu ----  BM=256, 256 threads
    lin_tiled<64, 32, 256, 32, 8, 4><<<cdiv(n, 256), 256, 0, stream>>>(xA, wl1, wr1, b1, Y, xB, n);
    agg4_kernel<32, true><<<cdiv(n * 8, BLK), BLK, 0, stream>>>((const float4*)Y, row_start, ssrc, inv_deg, (float4*)xB, n);

    // ---- layer 2: 32 -> 16, relu ----  naive (R1-measured class, ~20us)
    lin_naive<32, 16><<<cdiv(n * 16, BLK), BLK, 0, stream>>>(xB, wl2, wr2, b2, Y, xA, n);
    agg4_kernel<16, true><<<cdiv(n * 4, BLK), BLK, 0, stream>>>((const float4*)Y, row_start, ssrc, inv_deg, (float4*)xA, n);

    // ---- layer 3: 16 -> 9, no relu ----
    lin_naive<16, 9><<<cdiv(n * 9, BLK), BLK, 0, stream>>>(xA, wl3, wr3, b3, Y, out, n);
    agg_kernel<9, false><<<cdiv(n * 9, BLK), BLK, 0, stream>>>(Y, row_start, ssrc, inv_deg, out, n);
}

// Round 7
// 402.548 us; speedup vs baseline: 1.7491x; 1.0581x over previous
//
#include <hip/hip_runtime.h>
#include <hip/hip_bf16.h>

// SageNet: 4-layer GraphSAGE (mean aggr), N=100000 nodes, E=600000 edges.
// DIMS: 128 -> 64 -> 32 -> 16 -> 9.
//
// agg(x) @ w_l == agg(x @ w_l)  (mean aggregation is linear), so per layer:
//   lin:  y = x @ wl ; z = x @ wr + b   (layers 0-1: tiled dual-GEMM;
//                                        layers 2-3: naive per-node, tiny work)
//   agg:  out[n] = act(z[n] + (sum_{in-edges} y[src]) * inv_deg[n])
// Pull-style CSR aggregation (built on device), zero float atomics.
//
// R3: lin_tiled<32,16,BM=256,128thr> was genuinely ~200us (grid 391, ~1.5
//     blocks/CU). Tiny layers use the R1-measured naive class instead.
// R6: lin0 all metrics ~25% (VALUBusy 26 / Occ 26 / HBM 22%) = latency-bound,
//     too few waves: 33KB LDS -> 4 blocks/CU, grid 782 -> ~3 resident.
//     Fix: BM=64 tile, weights read from global (L1/L2-resident, coalesced
//     float4) instead of LDS -> 8.7KB LDS, 8 blocks/CU, grid 1563.
//     Bank conflicts measured negligible (~2us/CU total) - not addressed.

#define BLK 256

// ---------------- CSR build ----------------

__global__ void hist_kernel(const int* __restrict__ dst, int* __restrict__ deg, int e) {
    int t = blockIdx.x * blockDim.x + threadIdx.x;
    if (t < e) atomicAdd(&deg[dst[t]], 1);
}

__global__ void scan1_kernel(const int* __restrict__ deg, int* __restrict__ excl,
                             int* __restrict__ bsums, int n) {
    __shared__ int sm[256];
    int base = blockIdx.x * 1024;
    int t = threadIdx.x;
    int v[4];
    int s = 0;
    #pragma unroll
    for (int j = 0; j < 4; j++) {
        int i = base + t * 4 + j;
        v[j] = (i < n) ? deg[i] : 0;
        s += v[j];
    }
    sm[t] = s;
    __syncthreads();
    for (int off = 1; off < 256; off <<= 1) {
        int x = (t >= off) ? sm[t - off] : 0;
        __syncthreads();
        sm[t] += x;
        __syncthreads();
    }
    int excl_t = sm[t] - s;
    if (t == 255) bsums[blockIdx.x] = sm[255];
    int run = excl_t;
    #pragma unroll
    for (int j = 0; j < 4; j++) {
        int i = base + t * 4 + j;
        if (i < n) excl[i] = run;
        run += v[j];
    }
}

__global__ void scan2_kernel(int* __restrict__ bsums, int nb) {
    __shared__ int sm[256];
    int t = threadIdx.x;
    int v = (t < nb) ? bsums[t] : 0;
    sm[t] = v;
    __syncthreads();
    for (int off = 1; off < 256; off <<= 1) {
        int x = (t >= off) ? sm[t - off] : 0;
        __syncthreads();
        sm[t] += x;
        __syncthreads();
    }
    if (t < nb) bsums[t] = sm[t] - v;
}

__global__ void scan3_kernel(const int* __restrict__ deg, int* __restrict__ row_start,
                             const int* __restrict__ bsums, int* __restrict__ cursor,
                             float* __restrict__ inv_deg, int n, int e) {
    int t = blockIdx.x * blockDim.x + threadIdx.x;
    if (t < n) {
        int rs = row_start[t] + bsums[t >> 10];
        row_start[t] = rs;
        cursor[t] = rs;
        int d = deg[t];
        inv_deg[t] = 1.0f / (float)(d > 1 ? d : 1);
    }
    if (t == 0) row_start[n] = e;
}

__global__ void scatter_kernel(const int* __restrict__ src, const int* __restrict__ dst,
                               int* __restrict__ cursor, int* __restrict__ ssrc, int e) {
    int t = blockIdx.x * blockDim.x + threadIdx.x;
    if (t < e) {
        int p = atomicAdd(&cursor[dst[t]], 1);
        ssrc[p] = src[t];
    }
}

// ---------------- tiled dual-GEMM lin (layers 0-1) ----------------
// y = x @ wl ; z = x @ wr + b.
// x tile transposed in LDS (8.7KB only); weights read from global per k
// (identical across blocks -> L1/L2-resident, coalesced float4 per wave).

template <int FIN, int FOUT, int BM, int KC, int TM, int TN, int THREADS>
__global__ void lin_tiled2(const float* __restrict__ x, const float* __restrict__ wl,
                           const float* __restrict__ wr, const float* __restrict__ b,
                           float* __restrict__ y, float* __restrict__ z, int n) {
    constexpr int PAD = 4;
    constexpr int CPR = FOUT / TN;               // threads along f
    static_assert(THREADS == (BM / TM) * CPR, "thread shape mismatch");
    __shared__ float xT[KC][BM + PAD];

    const int tid = threadIdx.x;
    const int r = tid / CPR;
    const int c = tid % CPR;
    const int m0 = r * TM;
    const int f0 = c * TN;
    const int nodeBase = blockIdx.x * BM;

    float accy[TM][TN] = {};
    float accz[TM][TN] = {};

    for (int k0 = 0; k0 < FIN; k0 += KC) {
        // stage x^T (coalesced float4 global reads; ~4-way LDS write conflict
        // measured negligible)
        constexpr int XLOADS = (BM * KC) / (THREADS * 4);
        #pragma unroll
        for (int l = 0; l < XLOADS; l++) {
            int idx = (l * THREADS + tid) * 4;
            int node = idx / KC;
            int kk = idx % KC;
            float4 v = {0.f, 0.f, 0.f, 0.f};
            int gn = nodeBase + node;
            if (gn < n) v = *(const float4*)(x + (size_t)gn * FIN + k0 + kk);
            xT[kk + 0][node] = v.x;
            xT[kk + 1][node] = v.y;
            xT[kk + 2][node] = v.z;
            xT[kk + 3][node] = v.w;
        }
        __syncthreads();

        #pragma unroll 8
        for (int k = 0; k < KC; k++) {
            float a[TM];
            #pragma unroll
            for (int i = 0; i < TM; i += 4) *(float4*)&a[i] = *(const float4*)&xT[k][m0 + i];
            float4 blv = *(const float4*)(wl + (size_t)(k0 + k) * FOUT + f0);
            float4 brv = *(const float4*)(wr + (size_t)(k0 + k) * FOUT + f0);
            float bl[4] = {blv.x, blv.y, blv.z, blv.w};
            float br[4] = {brv.x, brv.y, brv.z, brv.w};
            #pragma unroll
            for (int i = 0; i < TM; i++)
                #pragma unroll
                for (int j = 0; j < TN; j++) {
                    accy[i][j] = fmaf(a[i], bl[j], accy[i][j]);
                    accz[i][j] = fmaf(a[i], br[j], accz[i][j]);
                }
        }
        __syncthreads();
    }

    float4 bv = *(const float4*)(b + f0);
    float bias[4] = {bv.x, bv.y, bv.z, bv.w};
    #pragma unroll
    for (int i = 0; i < TM; i++) {
        int gn = nodeBase + m0 + i;
        if (gn < n) {
            #pragma unroll
            for (int j = 0; j < TN; j += 4) {
                float4 vy = {accy[i][j], accy[i][j+1], accy[i][j+2], accy[i][j+3]};
                float4 vz = {accz[i][j] + bias[j], accz[i][j+1] + bias[j+1],
                             accz[i][j+2] + bias[j+2], accz[i][j+3] + bias[j+3]};
                *(float4*)(y + (size_t)gn * FOUT + f0 + j) = vy;
                *(float4*)(z + (size_t)gn * FOUT + f0 + j) = vz;
            }
        }
    }
}

// naive per-node lin for the tiny layers (2: 32->16, 3: 16->9).
template <int FIN, int FOUT>
__global__ void lin_naive(const float* __restrict__ x, const float* __restrict__ wl,
                          const float* __restrict__ wr, const float* __restrict__ b,
                          float* __restrict__ y, float* __restrict__ z, int n) {
    int t = blockIdx.x * blockDim.x + threadIdx.x;
    int node = t / FOUT;
    int f = t % FOUT;
    if (node >= n) return;
    const float* xr = x + (size_t)node * FIN;
    float accy = 0.f, accz = 0.f;
    #pragma unroll
    for (int k = 0; k < FIN; k++) {
        float xv = xr[k];
        accy = fmaf(xv, wl[k * FOUT + f], accy);
        accz = fmaf(xv, wr[k * FOUT + f], accz);
    }
    y[(size_t)node * FOUT + f] = accy;
    z[(size_t)node * FOUT + f] = accz + b[f];
}

// ---------------- aggregation ----------------

template <int FOUT, bool RELU>
__global__ void agg4_kernel(const float4* __restrict__ y4, const int* __restrict__ row_start,
                            const int* __restrict__ ssrc, const float* __restrict__ inv_deg,
                            float4* __restrict__ out4, int n) {
    constexpr int Q = FOUT / 4;
    int t = blockIdx.x * blockDim.x + threadIdx.x;
    int node = t / Q;
    int q = t % Q;
    if (node >= n) return;
    int e0 = row_start[node];
    int e1 = row_start[node + 1];
    float4 s = {0.f, 0.f, 0.f, 0.f};
    for (int e = e0; e < e1; e++) {
        int sn = ssrc[e];
        float4 v = y4[(size_t)sn * Q + q];
        s.x += v.x; s.y += v.y; s.z += v.z; s.w += v.w;
    }
    float id = inv_deg[node];
    float4 o = out4[(size_t)node * Q + q];
    o.x += s.x * id; o.y += s.y * id; o.z += s.z * id; o.w += s.w * id;
    if (RELU) {
        o.x = fmaxf(o.x, 0.f); o.y = fmaxf(o.y, 0.f);
        o.z = fmaxf(o.z, 0.f); o.w = fmaxf(o.w, 0.f);
    }
    out4[(size_t)node * Q + q] = o;
}

template <int FOUT, bool RELU>
__global__ void agg_kernel(const float* __restrict__ y, const int* __restrict__ row_start,
                           const int* __restrict__ ssrc, const float* __restrict__ inv_deg,
                           float* __restrict__ out, int n) {
    int t = blockIdx.x * blockDim.x + threadIdx.x;
    int node = t / FOUT;
    int f = t % FOUT;
    if (node >= n) return;
    int e0 = row_start[node];
    int e1 = row_start[node + 1];
    float s = 0.f;
    for (int e = e0; e < e1; e++) {
        int sn = ssrc[e];
        s += y[(size_t)sn * FOUT + f];
    }
    float v = out[(size_t)node * FOUT + f] + s * inv_deg[node];
    if (RELU) v = fmaxf(v, 0.f);
    out[(size_t)node * FOUT + f] = v;
}

// ---------------- launch ----------------

static inline int cdiv(int a, int b) { return (a + b - 1) / b; }

extern "C" void kernel_launch(void* const* d_in, const int* in_sizes, int n_in,
                              void* d_out, int out_size, void* d_ws, size_t ws_size,
                              hipStream_t stream) {
    const float* emb  = (const float*)d_in[0];
    const int*   eidx = (const int*)d_in[1];
    const float* wl0 = (const float*)d_in[3];
    const float* wr0 = (const float*)d_in[4];
    const float* b0  = (const float*)d_in[5];
    const float* wl1 = (const float*)d_in[6];
    const float* wr1 = (const float*)d_in[7];
    const float* b1  = (const float*)d_in[8];
    const float* wl2 = (const float*)d_in[9];
    const float* wr2 = (const float*)d_in[10];
    const float* b2  = (const float*)d_in[11];
    const float* wl3 = (const float*)d_in[12];
    const float* wr3 = (const float*)d_in[13];
    const float* b3  = (const float*)d_in[14];

    const int n = in_sizes[0] / 128;   // 100000
    const int e = in_sizes[1] / 2;     // 600000
    const int* src = eidx;
    const int* dst = eidx + e;

    char* ws = (char*)d_ws;
    size_t off = 0;
    auto alloc = [&](size_t bytes) -> void* {
        void* p = ws + off;
        off = (off + bytes + 255) & ~(size_t)255;
        return p;
    };
    int*   deg       = (int*)alloc((size_t)n * 4);
    float* inv_deg   = (float*)alloc((size_t)n * 4);
    int*   row_start = (int*)alloc(((size_t)n + 1) * 4);
    int*   cursor    = (int*)alloc((size_t)n * 4);
    int*   bsums     = (int*)alloc(1024 * 4);
    int*   ssrc      = (int*)alloc((size_t)e * 4);
    float* Y         = (float*)alloc((size_t)n * 64 * 4);
    float* xA        = (float*)alloc((size_t)n * 64 * 4);
    float* xB        = (float*)alloc((size_t)n * 32 * 4);
    (void)ws_size;

    // ---- CSR build ----
    hipMemsetAsync(deg, 0, (size_t)n * 4, stream);
    hist_kernel<<<cdiv(e, BLK), BLK, 0, stream>>>(dst, deg, e);
    int nchunks = cdiv(n, 1024);
    scan1_kernel<<<nchunks, 256, 0, stream>>>(deg, row_start, bsums, n);
    scan2_kernel<<<1, 256, 0, stream>>>(bsums, nchunks);
    scan3_kernel<<<cdiv(n, BLK), BLK, 0, stream>>>(deg, row_start, bsums, cursor, inv_deg, n, e);
    scatter_kernel<<<cdiv(e, BLK), BLK, 0, stream>>>(src, dst, cursor, ssrc, e);

    float* out = (float*)d_out;

    // ---- layer 0: 128 -> 64, relu ----  BM=64, 256 threads, 8.7KB LDS
    lin_tiled2<128, 64, 64, 32, 4, 4, 256><<<cdiv(n, 64), 256, 0, stream>>>(emb, wl0, wr0, b0, Y, xA, n);
    agg4_kernel<64, true><<<cdiv(n * 16, BLK), BLK, 0, stream>>>((const float4*)Y, row_start, ssrc, inv_deg, (float4*)xA, n);

    // ---- layer 1: 64 -> 32, relu ----  BM=64, 128 threads
    lin_tiled2<64, 32, 64, 32, 4, 4, 128><<<cdiv(n, 64), 128, 0, stream>>>(xA, wl1, wr1, b1, Y, xB, n);
    agg4_kernel<32, true><<<cdiv(n * 8, BLK), BLK, 0, stream>>>((const float4*)Y, row_start, ssrc, inv_deg, (float4*)xB, n);

    // ---- layer 2: 32 -> 16, relu ----  naive (R1-measured class)
    lin_naive<32, 16><<<cdiv(n * 16, BLK), BLK, 0, stream>>>(xB, wl2, wr2, b2, Y, xA, n);
    agg4_kernel<16, true><<<cdiv(n * 4, BLK), BLK, 0, stream>>>((const float4*)Y, row_start, ssrc, inv_deg, (float4*)xA, n);

    // ---- layer 3: 16 -> 9, no relu ----
    lin_naive<16, 9><<<cdiv(n * 9, BLK), BLK, 0, stream>>>(xA, wl3, wr3, b3, Y, out, n);
    agg_kernel<9, false><<<cdiv(n * 9, BLK), BLK, 0, stream>>>(Y, row_start, ssrc, inv_deg, out, n);
}

// Round 8
// 383.789 us; speedup vs baseline: 1.8346x; 1.0489x over previous
//
#include <hip/hip_runtime.h>
#include <hip/hip_bf16.h>

// SageNet: 4-layer GraphSAGE (mean aggr), N=100000 nodes, E=600000 edges.
// DIMS: 128 -> 64 -> 32 -> 16 -> 9.
//
// agg(x) @ w_l == agg(x @ w_l)  (mean aggregation is linear), so per layer:
//   lin:  y = x @ wl ; z = x @ wr + b   (layers 0-1: tiled dual-GEMM;
//                                        layers 2-3: naive per-node, tiny work)
//   agg:  out[n] = act(z[n] + (sum_{in-edges} y[src]) * inv_deg[n])
// Pull-style CSR aggregation (built on device), zero float atomics.
//
// R3: BM=256/128thr tiled lin (grid 391, 1.5 blocks/CU) genuinely ~200us.
// R6: 33KB-LDS tile -> occ 26%, latency-bound, 92us.
// R7: 8.7KB tile -> occ 37% (grid-limited: 1563 blocks = 3/CU), still 96us,
//     VALUBusy 25%. 32 FMA (64cyc) per k-step vs ~200cyc weight-load latency
//     can't be hidden by 3 waves/SIMD. Fix: TM=8 -> 64 FMA (128cyc) per
//     k-step, half the waves per unit work.

#define BLK 256

// ---------------- CSR build ----------------

__global__ void hist_kernel(const int* __restrict__ dst, int* __restrict__ deg, int e) {
    int t = blockIdx.x * blockDim.x + threadIdx.x;
    if (t < e) atomicAdd(&deg[dst[t]], 1);
}

__global__ void scan1_kernel(const int* __restrict__ deg, int* __restrict__ excl,
                             int* __restrict__ bsums, int n) {
    __shared__ int sm[256];
    int base = blockIdx.x * 1024;
    int t = threadIdx.x;
    int v[4];
    int s = 0;
    #pragma unroll
    for (int j = 0; j < 4; j++) {
        int i = base + t * 4 + j;
        v[j] = (i < n) ? deg[i] : 0;
        s += v[j];
    }
    sm[t] = s;
    __syncthreads();
    for (int off = 1; off < 256; off <<= 1) {
        int x = (t >= off) ? sm[t - off] : 0;
        __syncthreads();
        sm[t] += x;
        __syncthreads();
    }
    int excl_t = sm[t] - s;
    if (t == 255) bsums[blockIdx.x] = sm[255];
    int run = excl_t;
    #pragma unroll
    for (int j = 0; j < 4; j++) {
        int i = base + t * 4 + j;
        if (i < n) excl[i] = run;
        run += v[j];
    }
}

__global__ void scan2_kernel(int* __restrict__ bsums, int nb) {
    __shared__ int sm[256];
    int t = threadIdx.x;
    int v = (t < nb) ? bsums[t] : 0;
    sm[t] = v;
    __syncthreads();
    for (int off = 1; off < 256; off <<= 1) {
        int x = (t >= off) ? sm[t - off] : 0;
        __syncthreads();
        sm[t] += x;
        __syncthreads();
    }
    if (t < nb) bsums[t] = sm[t] - v;
}

__global__ void scan3_kernel(const int* __restrict__ deg, int* __restrict__ row_start,
                             const int* __restrict__ bsums, int* __restrict__ cursor,
                             float* __restrict__ inv_deg, int n, int e) {
    int t = blockIdx.x * blockDim.x + threadIdx.x;
    if (t < n) {
        int rs = row_start[t] + bsums[t >> 10];
        row_start[t] = rs;
        cursor[t] = rs;
        int d = deg[t];
        inv_deg[t] = 1.0f / (float)(d > 1 ? d : 1);
    }
    if (t == 0) row_start[n] = e;
}

__global__ void scatter_kernel(const int* __restrict__ src, const int* __restrict__ dst,
                               int* __restrict__ cursor, int* __restrict__ ssrc, int e) {
    int t = blockIdx.x * blockDim.x + threadIdx.x;
    if (t < e) {
        int p = atomicAdd(&cursor[dst[t]], 1);
        ssrc[p] = src[t];
    }
}

// ---------------- tiled dual-GEMM lin (layers 0-1) ----------------
// y = x @ wl ; z = x @ wr + b.
// x tile transposed in LDS; weights read from global per k (L1/L2-resident).

template <int FIN, int FOUT, int BM, int KC, int TM, int TN, int THREADS>
__global__ void lin_tiled2(const float* __restrict__ x, const float* __restrict__ wl,
                           const float* __restrict__ wr, const float* __restrict__ b,
                           float* __restrict__ y, float* __restrict__ z, int n) {
    constexpr int PAD = 4;
    constexpr int CPR = FOUT / TN;               // threads along f
    static_assert(THREADS == (BM / TM) * CPR, "thread shape mismatch");
    __shared__ float xT[KC][BM + PAD];

    const int tid = threadIdx.x;
    const int r = tid / CPR;
    const int c = tid % CPR;
    const int m0 = r * TM;
    const int f0 = c * TN;
    const int nodeBase = blockIdx.x * BM;

    float accy[TM][TN] = {};
    float accz[TM][TN] = {};

    for (int k0 = 0; k0 < FIN; k0 += KC) {
        constexpr int XLOADS = (BM * KC) / (THREADS * 4);
        #pragma unroll
        for (int l = 0; l < XLOADS; l++) {
            int idx = (l * THREADS + tid) * 4;
            int node = idx / KC;
            int kk = idx % KC;
            float4 v = {0.f, 0.f, 0.f, 0.f};
            int gn = nodeBase + node;
            if (gn < n) v = *(const float4*)(x + (size_t)gn * FIN + k0 + kk);
            xT[kk + 0][node] = v.x;
            xT[kk + 1][node] = v.y;
            xT[kk + 2][node] = v.z;
            xT[kk + 3][node] = v.w;
        }
        __syncthreads();

        #pragma unroll 8
        for (int k = 0; k < KC; k++) {
            float a[TM];
            #pragma unroll
            for (int i = 0; i < TM; i += 4) *(float4*)&a[i] = *(const float4*)&xT[k][m0 + i];
            float4 blv = *(const float4*)(wl + (size_t)(k0 + k) * FOUT + f0);
            float4 brv = *(const float4*)(wr + (size_t)(k0 + k) * FOUT + f0);
            float bl[4] = {blv.x, blv.y, blv.z, blv.w};
            float br[4] = {brv.x, brv.y, brv.z, brv.w};
            #pragma unroll
            for (int i = 0; i < TM; i++)
                #pragma unroll
                for (int j = 0; j < TN; j++) {
                    accy[i][j] = fmaf(a[i], bl[j], accy[i][j]);
                    accz[i][j] = fmaf(a[i], br[j], accz[i][j]);
                }
        }
        __syncthreads();
    }

    float4 bv = *(const float4*)(b + f0);
    float bias[4] = {bv.x, bv.y, bv.z, bv.w};
    #pragma unroll
    for (int i = 0; i < TM; i++) {
        int gn = nodeBase + m0 + i;
        if (gn < n) {
            #pragma unroll
            for (int j = 0; j < TN; j += 4) {
                float4 vy = {accy[i][j], accy[i][j+1], accy[i][j+2], accy[i][j+3]};
                float4 vz = {accz[i][j] + bias[j], accz[i][j+1] + bias[j+1],
                             accz[i][j+2] + bias[j+2], accz[i][j+3] + bias[j+3]};
                *(float4*)(y + (size_t)gn * FOUT + f0 + j) = vy;
                *(float4*)(z + (size_t)gn * FOUT + f0 + j) = vz;
            }
        }
    }
}

// naive per-node lin for the tiny layers (2: 32->16, 3: 16->9).
template <int FIN, int FOUT>
__global__ void lin_naive(const float* __restrict__ x, const float* __restrict__ wl,
                          const float* __restrict__ wr, const float* __restrict__ b,
                          float* __restrict__ y, float* __restrict__ z, int n) {
    int t = blockIdx.x * blockDim.x + threadIdx.x;
    int node = t / FOUT;
    int f = t % FOUT;
    if (node >= n) return;
    const float* xr = x + (size_t)node * FIN;
    float accy = 0.f, accz = 0.f;
    #pragma unroll
    for (int k = 0; k < FIN; k++) {
        float xv = xr[k];
        accy = fmaf(xv, wl[k * FOUT + f], accy);
        accz = fmaf(xv, wr[k * FOUT + f], accz);
    }
    y[(size_t)node * FOUT + f] = accy;
    z[(size_t)node * FOUT + f] = accz + b[f];
}

// ---------------- aggregation ----------------
// 2-edge unroll: both ssrc loads + both row gathers issued before consuming
// (doubles outstanding loads on the latency-critical gather chain).

template <int FOUT, bool RELU>
__global__ void agg4_kernel(const float4* __restrict__ y4, const int* __restrict__ row_start,
                            const int* __restrict__ ssrc, const float* __restrict__ inv_deg,
                            float4* __restrict__ out4, int n) {
    constexpr int Q = FOUT / 4;
    int t = blockIdx.x * blockDim.x + threadIdx.x;
    int node = t / Q;
    int q = t % Q;
    if (node >= n) return;
    int e0 = row_start[node];
    int e1 = row_start[node + 1];
    float4 s = {0.f, 0.f, 0.f, 0.f};
    int e = e0;
    for (; e + 1 < e1; e += 2) {
        int sn0 = ssrc[e];
        int sn1 = ssrc[e + 1];
        float4 v0 = y4[(size_t)sn0 * Q + q];
        float4 v1 = y4[(size_t)sn1 * Q + q];
        s.x += v0.x; s.y += v0.y; s.z += v0.z; s.w += v0.w;
        s.x += v1.x; s.y += v1.y; s.z += v1.z; s.w += v1.w;
    }
    if (e < e1) {
        int sn = ssrc[e];
        float4 v = y4[(size_t)sn * Q + q];
        s.x += v.x; s.y += v.y; s.z += v.z; s.w += v.w;
    }
    float id = inv_deg[node];
    float4 o = out4[(size_t)node * Q + q];
    o.x += s.x * id; o.y += s.y * id; o.z += s.z * id; o.w += s.w * id;
    if (RELU) {
        o.x = fmaxf(o.x, 0.f); o.y = fmaxf(o.y, 0.f);
        o.z = fmaxf(o.z, 0.f); o.w = fmaxf(o.w, 0.f);
    }
    out4[(size_t)node * Q + q] = o;
}

template <int FOUT, bool RELU>
__global__ void agg_kernel(const float* __restrict__ y, const int* __restrict__ row_start,
                           const int* __restrict__ ssrc, const float* __restrict__ inv_deg,
                           float* __restrict__ out, int n) {
    int t = blockIdx.x * blockDim.x + threadIdx.x;
    int node = t / FOUT;
    int f = t % FOUT;
    if (node >= n) return;
    int e0 = row_start[node];
    int e1 = row_start[node + 1];
    float s = 0.f;
    int e = e0;
    for (; e + 1 < e1; e += 2) {
        int sn0 = ssrc[e];
        int sn1 = ssrc[e + 1];
        float v0 = y[(size_t)sn0 * FOUT + f];
        float v1 = y[(size_t)sn1 * FOUT + f];
        s += v0 + v1;
    }
    if (e < e1) s += y[(size_t)ssrc[e] * FOUT + f];
    float v = out[(size_t)node * FOUT + f] + s * inv_deg[node];
    if (RELU) v = fmaxf(v, 0.f);
    out[(size_t)node * FOUT + f] = v;
}

// ---------------- launch ----------------

static inline int cdiv(int a, int b) { return (a + b - 1) / b; }

extern "C" void kernel_launch(void* const* d_in, const int* in_sizes, int n_in,
                              void* d_out, int out_size, void* d_ws, size_t ws_size,
                              hipStream_t stream) {
    const float* emb  = (const float*)d_in[0];
    const int*   eidx = (const int*)d_in[1];
    const float* wl0 = (const float*)d_in[3];
    const float* wr0 = (const float*)d_in[4];
    const float* b0  = (const float*)d_in[5];
    const float* wl1 = (const float*)d_in[6];
    const float* wr1 = (const float*)d_in[7];
    const float* b1  = (const float*)d_in[8];
    const float* wl2 = (const float*)d_in[9];
    const float* wr2 = (const float*)d_in[10];
    const float* b2  = (const float*)d_in[11];
    const float* wl3 = (const float*)d_in[12];
    const float* wr3 = (const float*)d_in[13];
    const float* b3  = (const float*)d_in[14];

    const int n = in_sizes[0] / 128;   // 100000
    const int e = in_sizes[1] / 2;     // 600000
    const int* src = eidx;
    const int* dst = eidx + e;

    char* ws = (char*)d_ws;
    size_t off = 0;
    auto alloc = [&](size_t bytes) -> void* {
        void* p = ws + off;
        off = (off + bytes + 255) & ~(size_t)255;
        return p;
    };
    int*   deg       = (int*)alloc((size_t)n * 4);
    float* inv_deg   = (float*)alloc((size_t)n * 4);
    int*   row_start = (int*)alloc(((size_t)n + 1) * 4);
    int*   cursor    = (int*)alloc((size_t)n * 4);
    int*   bsums     = (int*)alloc(1024 * 4);
    int*   ssrc      = (int*)alloc((size_t)e * 4);
    float* Y         = (float*)alloc((size_t)n * 64 * 4);
    float* xA        = (float*)alloc((size_t)n * 64 * 4);
    float* xB        = (float*)alloc((size_t)n * 32 * 4);
    (void)ws_size;

    // ---- CSR build ----
    hipMemsetAsync(deg, 0, (size_t)n * 4, stream);
    hist_kernel<<<cdiv(e, BLK), BLK, 0, stream>>>(dst, deg, e);
    int nchunks = cdiv(n, 1024);
    scan1_kernel<<<nchunks, 256, 0, stream>>>(deg, row_start, bsums, n);
    scan2_kernel<<<1, 256, 0, stream>>>(bsums, nchunks);
    scan3_kernel<<<cdiv(n, BLK), BLK, 0, stream>>>(deg, row_start, bsums, cursor, inv_deg, n, e);
    scatter_kernel<<<cdiv(e, BLK), BLK, 0, stream>>>(src, dst, cursor, ssrc, e);

    float* out = (float*)d_out;

    // ---- layer 0: 128 -> 64, relu ----  BM=128, TM=8, 256 threads, 16.9KB LDS
    lin_tiled2<128, 64, 128, 32, 8, 4, 256><<<cdiv(n, 128), 256, 0, stream>>>(emb, wl0, wr0, b0, Y, xA, n);
    agg4_kernel<64, true><<<cdiv(n * 16, BLK), BLK, 0, stream>>>((const float4*)Y, row_start, ssrc, inv_deg, (float4*)xA, n);

    // ---- layer 1: 64 -> 32, relu ----  BM=64, 128 threads (unchanged)
    lin_tiled2<64, 32, 64, 32, 4, 4, 128><<<cdiv(n, 64), 128, 0, stream>>>(xA, wl1, wr1, b1, Y, xB, n);
    agg4_kernel<32, true><<<cdiv(n * 8, BLK), BLK, 0, stream>>>((const float4*)Y, row_start, ssrc, inv_deg, (float4*)xB, n);

    // ---- layer 2: 32 -> 16, relu ----  naive (R1-measured class)
    lin_naive<32, 16><<<cdiv(n * 16, BLK), BLK, 0, stream>>>(xB, wl2, wr2, b2, Y, xA, n);
    agg4_kernel<16, true><<<cdiv(n * 4, BLK), BLK, 0, stream>>>((const float4*)Y, row_start, ssrc, inv_deg, (float4*)xA, n);

    // ---- layer 3: 16 -> 9, no relu ----
    lin_naive<16, 9><<<cdiv(n * 9, BLK), BLK, 0, stream>>>(xA, wl3, wr3, b3, Y, out, n);
    agg_kernel<9, false><<<cdiv(n * 9, BLK), BLK, 0, stream>>>(Y, row_start, ssrc, inv_deg, out, n);
}